// Round 1
// baseline (333.729 us; speedup 1.0000x reference)
//
#include <hip/hip_runtime.h>

// Anchor generation: out[(a,y,x), 0..3] = {cx-w2[a], cy-h2[a], cx+w2[a], cy+h2[a]}
// cx=(x+0.5)*8, cy=(y+0.5)*8 ; fh=fw=1024, 9 anchor shapes.
// Pure streaming-write kernel, ~151 MB fp32 output.

// w2 = scale*sqrt(ratio)/2, h2 = scale/sqrt(ratio)/2 for
// scales (8,16,32) x ratios (0.5,1,2), a = scale_idx*3 + ratio_idx.
__device__ __constant__ float kW2[9] = {
    2.82842712f, 4.0f,  5.65685425f,
    5.65685425f, 8.0f,  11.3137085f,
    11.3137085f, 16.0f, 22.627417f
};
__device__ __constant__ float kH2[9] = {
    5.65685425f,  4.0f,  2.82842712f,
    11.3137085f,  8.0f,  5.65685425f,
    22.627417f,   16.0f, 11.3137085f
};

__global__ __launch_bounds__(256) void anchor_gen_kernel(float4* __restrict__ out) {
    // total float4 elements = 9 << 20; grid covers it exactly.
    const int i = blockIdx.x * 256 + threadIdx.x;
    const int a   = i >> 20;           // anchor-shape index, uniform per block
    const int rem = i & ((1 << 20) - 1);
    const float x = (float)(rem & 1023);
    const float y = (float)(rem >> 10);
    const float cx = x * 8.0f + 4.0f;  // (x+0.5)*8
    const float cy = y * 8.0f + 4.0f;
    const float w2 = kW2[a];
    const float h2 = kH2[a];
    out[i] = make_float4(cx - w2, cy - h2, cx + w2, cy + h2);
}

extern "C" void kernel_launch(void* const* d_in, const int* in_sizes, int n_in,
                              void* d_out, int out_size, void* d_ws, size_t ws_size,
                              hipStream_t stream) {
    (void)d_in; (void)in_sizes; (void)n_in; (void)d_ws; (void)ws_size;
    // out_size = 9*1024*1024*4 floats = 9<<20 float4s
    const int total4 = 9 << 20;
    const int block = 256;
    const int grid = total4 / block;   // 36864, divides exactly
    anchor_gen_kernel<<<grid, block, 0, stream>>>((float4*)d_out);
}